// Round 2
// baseline (665.602 us; speedup 1.0000x reference)
//
#include <hip/hip_runtime.h>

// 5x5 box filter, zero padding, fp32 in/out, 8192x8192.
// Memory floor ~= (read 256 MiB + write 256 MiB) / 6.3 TB/s ~= 85 us.
// R1: latency-bound (occ 19%, VALU 8.5%, HBM 31%) -> raise occupancy/TLP.

constexpr int H = 8192;
constexpr int W = 8192;
constexpr int ROWS = 16;   // output rows per block (halo 20/16, L3-absorbed)
constexpr int TPB  = 256;  // threads per block; each thread does 4 columns

typedef float f4 __attribute__((ext_vector_type(4)));
typedef f4 __attribute__((aligned(4))) f4u;   // allow 8B-aligned vector loads

__global__ __launch_bounds__(TPB, 6)   // cap ~85 VGPR -> 6 waves/SIMD
void box5_kernel(const float* __restrict__ in, float* __restrict__ out) {
    const int c0 = blockIdx.x * (TPB * 4) + threadIdx.x * 4;  // first of 4 output cols
    const int y0 = blockIdx.y * ROWS;                          // first output row
    // Interior iff window [c0-2, c0+5] fully inside [0, W)
    const bool interior = (c0 >= 2) && (c0 + 5 < W);

    float h[5][4];  // ring buffer of horizontal 5-sums for 5 consecutive rows

    auto load_h = [&](int y, float* hh) {
        if ((unsigned)y >= (unsigned)H) {
            hh[0] = hh[1] = hh[2] = hh[3] = 0.0f;
            return;
        }
        const float* rp = in + (size_t)y * W;
        float w[8];
        if (interior) {
            // c0 is a multiple of 4 -> (c0-2) and (c0+2) are 8B-aligned
            f4 a = *(const f4u*)(rp + c0 - 2);
            f4 b = *(const f4u*)(rp + c0 + 2);
            w[0] = a[0]; w[1] = a[1]; w[2] = a[2]; w[3] = a[3];
            w[4] = b[0]; w[5] = b[1]; w[6] = b[2]; w[7] = b[3];
        } else {
            #pragma unroll
            for (int k = 0; k < 8; ++k) {
                int idx = c0 - 2 + k;
                w[k] = ((unsigned)idx < (unsigned)W) ? rp[idx] : 0.0f;
            }
        }
        #pragma unroll
        for (int j = 0; j < 4; ++j)
            hh[j] = ((w[j] + w[j + 1]) + (w[j + 2] + w[j + 3])) + w[j + 4];
    };

    // Prologue: rows y0-2 .. y0+1 into ring slots 0..3
    #pragma unroll
    for (int i = 0; i < 4; ++i)
        load_h(y0 - 2 + i, h[i]);

    const float inv25 = 1.0f / 25.0f;

    #pragma unroll
    for (int i = 0; i < ROWS; ++i) {
        const int y = y0 + i;
        load_h(y + 2, h[(i + 4) % 5]);  // compile-time index (full unroll)
        f4 o;
        #pragma unroll
        for (int j = 0; j < 4; ++j) {
            o[j] = (((h[0][j] + h[1][j]) + (h[2][j] + h[3][j])) + h[4][j]) * inv25;
        }
        // Output is never re-read: non-temporal store keeps L3 for the input.
        __builtin_nontemporal_store(o, (f4*)(out + (size_t)y * W + c0));
    }
}

extern "C" void kernel_launch(void* const* d_in, const int* in_sizes, int n_in,
                              void* d_out, int out_size, void* d_ws, size_t ws_size,
                              hipStream_t stream) {
    const float* in = (const float*)d_in[0];
    // d_in[1] is the uniform 5x5 kernel = ones/25; folded into inv25 constant.
    float* out = (float*)d_out;
    dim3 grid(W / (TPB * 4), H / ROWS);  // (8, 512) = 4096 blocks
    box5_kernel<<<grid, dim3(TPB), 0, stream>>>(in, out);
}

// Round 3
// 646.794 us; speedup vs baseline: 1.0291x; 1.0291x over previous
//
#include <hip/hip_runtime.h>

// 5x5 box filter, zero padding, fp32 in/out, 8192x8192.
// Memory floor ~= (read 256 MiB + write 256 MiB) / 6.3 TB/s ~= 85 us.
// R1: latency-bound (occ 19%) -> launch_bounds cap.
// R2: nontemporal stores caused RMW write amplification (WRITE 1.75 GB) -> revert.

constexpr int H = 8192;
constexpr int W = 8192;
constexpr int ROWS = 16;   // output rows per block (halo 20/16, mostly L2/L3-absorbed)
constexpr int TPB  = 256;  // threads per block; each thread does 4 columns

typedef float f4 __attribute__((ext_vector_type(4)));
typedef f4 __attribute__((aligned(4))) f4u;   // allow 8B-aligned vector loads

__global__ __launch_bounds__(TPB, 6)   // VGPR cap -> 6 waves/SIMD (R2: VGPR=40, occ 60%)
void box5_kernel(const float* __restrict__ in, float* __restrict__ out) {
    const int c0 = blockIdx.x * (TPB * 4) + threadIdx.x * 4;  // first of 4 output cols
    const int y0 = blockIdx.y * ROWS;                          // first output row
    // Interior iff window [c0-2, c0+5] fully inside [0, W)
    const bool interior = (c0 >= 2) && (c0 + 5 < W);

    float h[5][4];  // ring buffer of horizontal 5-sums for 5 consecutive rows

    auto load_h = [&](int y, float* hh) {
        if ((unsigned)y >= (unsigned)H) {
            hh[0] = hh[1] = hh[2] = hh[3] = 0.0f;
            return;
        }
        const float* rp = in + (size_t)y * W;
        float w[8];
        if (interior) {
            // c0 is a multiple of 4 -> (c0-2) and (c0+2) are 8B-aligned
            f4 a = *(const f4u*)(rp + c0 - 2);
            f4 b = *(const f4u*)(rp + c0 + 2);
            w[0] = a[0]; w[1] = a[1]; w[2] = a[2]; w[3] = a[3];
            w[4] = b[0]; w[5] = b[1]; w[6] = b[2]; w[7] = b[3];
        } else {
            #pragma unroll
            for (int k = 0; k < 8; ++k) {
                int idx = c0 - 2 + k;
                w[k] = ((unsigned)idx < (unsigned)W) ? rp[idx] : 0.0f;
            }
        }
        #pragma unroll
        for (int j = 0; j < 4; ++j)
            hh[j] = ((w[j] + w[j + 1]) + (w[j + 2] + w[j + 3])) + w[j + 4];
    };

    // Prologue: rows y0-2 .. y0+1 into ring slots 0..3
    #pragma unroll
    for (int i = 0; i < 4; ++i)
        load_h(y0 - 2 + i, h[i]);

    const float inv25 = 1.0f / 25.0f;

    #pragma unroll
    for (int i = 0; i < ROWS; ++i) {
        const int y = y0 + i;
        load_h(y + 2, h[(i + 4) % 5]);  // compile-time index (full unroll)
        f4 o;
        #pragma unroll
        for (int j = 0; j < 4; ++j) {
            o[j] = (((h[0][j] + h[1][j]) + (h[2][j] + h[3][j])) + h[4][j]) * inv25;
        }
        *(f4*)(out + (size_t)y * W + c0) = o;  // plain write-back store (16B aligned)
    }
}

extern "C" void kernel_launch(void* const* d_in, const int* in_sizes, int n_in,
                              void* d_out, int out_size, void* d_ws, size_t ws_size,
                              hipStream_t stream) {
    const float* in = (const float*)d_in[0];
    // d_in[1] is the uniform 5x5 kernel = ones/25; folded into inv25 constant.
    float* out = (float*)d_out;
    dim3 grid(W / (TPB * 4), H / ROWS);  // (8, 512) = 4096 blocks
    box5_kernel<<<grid, dim3(TPB), 0, stream>>>(in, out);
}

// Round 4
// 168.880 us; speedup vs baseline: 3.9413x; 3.8299x over previous
//
#include <hip/hip_runtime.h>

// 5x5 box filter, zero padding, fp32 in/out, 8192x8192.
// Memory floor ~= (read 256 MiB + write 256 MiB) / 6.3 TB/s ~= 85 us.
// R1: 155us, VGPR=120, occ 19%, HBM 2.5 TB/s (latency-bound).
// R2/R3: __launch_bounds__(,6) cap -> private arrays demoted to scratch
//        (VGPR 40, WRITE 1.75GB, 650us). NEVER cap below natural usage here.
// R4: R1 structure, ROWS 32->16 (4096 blocks) for residency/balance.

constexpr int H = 8192;
constexpr int W = 8192;
constexpr int ROWS = 16;   // output rows per block (halo 20/16, L3-absorbed)
constexpr int TPB  = 256;  // threads per block; each thread does 4 columns

typedef float f4 __attribute__((ext_vector_type(4)));
typedef f4 __attribute__((aligned(4))) f4u;   // allow 8B-aligned vector loads

__global__ __launch_bounds__(TPB)   // no waves-per-EU cap (R2/R3 post-mortem)
void box5_kernel(const float* __restrict__ in, float* __restrict__ out) {
    const int c0 = blockIdx.x * (TPB * 4) + threadIdx.x * 4;  // first of 4 output cols
    const int y0 = blockIdx.y * ROWS;                          // first output row
    // Interior iff window [c0-2, c0+5] fully inside [0, W)
    const bool interior = (c0 >= 2) && (c0 + 5 < W);

    float h[5][4];  // ring buffer of horizontal 5-sums for 5 consecutive rows

    auto load_h = [&](int y, float* hh) {
        if ((unsigned)y >= (unsigned)H) {
            hh[0] = hh[1] = hh[2] = hh[3] = 0.0f;
            return;
        }
        const float* rp = in + (size_t)y * W;
        float w[8];
        if (interior) {
            // c0 is a multiple of 4 -> (c0-2) and (c0+2) are 8B-aligned
            f4 a = *(const f4u*)(rp + c0 - 2);
            f4 b = *(const f4u*)(rp + c0 + 2);
            w[0] = a[0]; w[1] = a[1]; w[2] = a[2]; w[3] = a[3];
            w[4] = b[0]; w[5] = b[1]; w[6] = b[2]; w[7] = b[3];
        } else {
            #pragma unroll
            for (int k = 0; k < 8; ++k) {
                int idx = c0 - 2 + k;
                w[k] = ((unsigned)idx < (unsigned)W) ? rp[idx] : 0.0f;
            }
        }
        #pragma unroll
        for (int j = 0; j < 4; ++j)
            hh[j] = ((w[j] + w[j + 1]) + (w[j + 2] + w[j + 3])) + w[j + 4];
    };

    // Prologue: rows y0-2 .. y0+1 into ring slots 0..3
    #pragma unroll
    for (int i = 0; i < 4; ++i)
        load_h(y0 - 2 + i, h[i]);

    const float inv25 = 1.0f / 25.0f;

    #pragma unroll
    for (int i = 0; i < ROWS; ++i) {
        const int y = y0 + i;
        load_h(y + 2, h[(i + 4) % 5]);  // compile-time index (full unroll)
        f4 o;
        #pragma unroll
        for (int j = 0; j < 4; ++j) {
            o[j] = (((h[0][j] + h[1][j]) + (h[2][j] + h[3][j])) + h[4][j]) * inv25;
        }
        *(f4*)(out + (size_t)y * W + c0) = o;  // plain write-back store (16B aligned)
    }
}

extern "C" void kernel_launch(void* const* d_in, const int* in_sizes, int n_in,
                              void* d_out, int out_size, void* d_ws, size_t ws_size,
                              hipStream_t stream) {
    const float* in = (const float*)d_in[0];
    // d_in[1] is the uniform 5x5 kernel = ones/25; folded into inv25 constant.
    float* out = (float*)d_out;
    dim3 grid(W / (TPB * 4), H / ROWS);  // (8, 512) = 4096 blocks
    box5_kernel<<<grid, dim3(TPB), 0, stream>>>(in, out);
}

// Round 5
// 116.353 us; speedup vs baseline: 5.7205x; 1.4514x over previous
//
#include <hip/hip_runtime.h>

// 5x5 box filter, zero pad, fp32, 8192x8192. HBM floor ~= 512MiB/6.3TBps ~= 85us.
// R1/R4: register-ring streaming = latency-bound (~2.6 TB/s, VALU 10%) --
//        <1 load in flight/wave. Grid shape changes did nothing.
// R2/R3: __launch_bounds__ waves-per-EU cap => scratch spill catastrophe. Never cap.
// R5: LDS-staged tile: 10 independent f4 loads/thread (bulk MLP) + conflict-free
//     ds_read_b128 compute phase.

constexpr int H = 8192, W = 8192;
constexpr int TPB = 256;
constexpr int TC  = 256;            // output tile cols
constexpr int TR  = 32;             // output tile rows
constexpr int LR  = TR + 4;         // 36 staged rows
constexpr int LCF = TC + 8;         // 264 staged floats per row (pitch 1056 B)
constexpr int NCHUNK = LCF / 4;     // 66 f4 chunks per row
constexpr int TOTCH  = LR * NCHUNK; // 2376 chunks per tile

typedef float f4 __attribute__((ext_vector_type(4)));

__global__ __launch_bounds__(TPB)
void box5_kernel(const float* __restrict__ in, float* __restrict__ out) {
    __shared__ float lds[LR * LCF];          // 38016 B -> 4 blocks/CU
    const int cb  = blockIdx.x * TC;
    const int rb  = blockIdx.y * TR;
    const int tid = threadIdx.x;

    // ---- Phase 1: bulk stage (10 independent predicated f4 loads) ----
    #pragma unroll
    for (int it = 0; it < (TOTCH + TPB - 1) / TPB; ++it) {
        const int lin = tid + it * TPB;
        if (lin < TOTCH) {                    // compile-time true for it<9
            const int lr = lin / NCHUNK;      // staged row 0..35
            const int lc = lin - lr * NCHUNK; // chunk 0..65
            const int gr = rb - 2 + lr;
            const int gc = cb - 4 + lc * 4;   // mult of 4 -> 16B aligned, no straddle
            f4 v = {0.f, 0.f, 0.f, 0.f};
            if ((unsigned)gr < (unsigned)H && (unsigned)gc < (unsigned)W)
                v = *(const f4*)(in + (size_t)gr * W + gc);
            *(f4*)(&lds[lr * LCF + lc * 4]) = v;  // consecutive tid -> 16B stride
        }
    }
    __syncthreads();

    // ---- Phase 2: horizontal 5-sums from LDS + vertical ring ----
    const int lx = tid & 63;                 // column group within the 256-col tile
    const int ly = tid >> 6;                 // row sub-band (8 rows each)
    const int colf = lx * 4;                 // local float offset of chunk A
    const int o0 = ly * 8;

    float h[5][4];                           // ring of horizontal 5-sums
    auto hrow = [&](int lraw, float* hh) {   // lraw = local staged row
        const float* p = &lds[lraw * LCF + colf];
        f4 A = *(const f4*)(p);              // lane stride 16B -> conflict-free
        f4 B = *(const f4*)(p + 4);
        f4 C = *(const f4*)(p + 8);
        hh[0] = ((A[2] + A[3]) + (B[0] + B[1])) + B[2];
        hh[1] = ((A[3] + B[0]) + (B[1] + B[2])) + B[3];
        hh[2] = ((B[0] + B[1]) + (B[2] + B[3])) + C[0];
        hh[3] = ((B[1] + B[2]) + (B[3] + C[0])) + C[1];
    };

    #pragma unroll
    for (int k = 0; k < 4; ++k) hrow(o0 + k, h[k]);

    const float inv25 = 1.0f / 25.0f;
    float* outp = out + (size_t)(rb + o0) * W + cb + colf;

    #pragma unroll
    for (int i = 0; i < 8; ++i) {
        hrow(o0 + i + 4, h[(i + 4) % 5]);    // compile-time ring index
        f4 ov;
        #pragma unroll
        for (int j = 0; j < 4; ++j)
            ov[j] = (((h[0][j] + h[1][j]) + (h[2][j] + h[3][j])) + h[4][j]) * inv25;
        *(f4*)(outp) = ov;                   // aligned, coalesced
        outp += W;
    }
}

extern "C" void kernel_launch(void* const* d_in, const int* in_sizes, int n_in,
                              void* d_out, int out_size, void* d_ws, size_t ws_size,
                              hipStream_t stream) {
    const float* in = (const float*)d_in[0];
    // d_in[1] is the uniform 5x5 kernel = ones/25; folded into inv25.
    float* out = (float*)d_out;
    dim3 grid(W / TC, H / TR);               // (32, 256) = 8192 blocks
    box5_kernel<<<grid, dim3(TPB), 0, stream>>>(in, out);
}

// Round 6
// 102.527 us; speedup vs baseline: 6.4920x; 1.1349x over previous
//
#include <hip/hip_runtime.h>

// 5x5 box filter, zero pad, fp32, 8192x8192. HBM floor ~= 512MiB/6.3TBps ~= 85us.
// R1/R4: register-ring streaming = latency-bound (~2.6 TB/s). 168us.
// R2/R3: __launch_bounds__ waves-per-EU cap => scratch spill catastrophe. Never cap.
// R5: LDS-staged 256x32 tile, 4 blocks/CU: 116us (~75% of achievable BW).
// R6: async global_load_lds staging (no VGPR round-trip) + TR=16 (21KB LDS ->
//     7 blocks/CU) for stage/compute overlap across blocks.

constexpr int H = 8192, W = 8192;
constexpr int TPB = 256;
constexpr int TC  = 256;            // output tile cols
constexpr int TR  = 16;             // output tile rows
constexpr int LR  = TR + 4;         // 20 staged rows
constexpr int LCF = TC + 8;         // 264 staged floats per row (pitch 1056 B)
constexpr int NCHUNK = LCF / 4;     // 66 f4 chunks per row
constexpr int TOTCH  = LR * NCHUNK; // 1320 chunks per tile

typedef float f4 __attribute__((ext_vector_type(4)));

#if defined(__has_builtin)
#  if __has_builtin(__builtin_amdgcn_global_load_lds)
#    define HAS_GLL 1
#  else
#    define HAS_GLL 0
#  endif
#else
#  define HAS_GLL 0
#endif

#if HAS_GLL
__device__ __forceinline__ void gload_lds16(const float* g, float* l) {
    __builtin_amdgcn_global_load_lds(
        (const __attribute__((address_space(1))) void*)g,
        (__attribute__((address_space(3))) void*)l,
        16, 0, 0);
}
#endif

__global__ __launch_bounds__(TPB)
void box5_kernel(const float* __restrict__ in, float* __restrict__ out) {
    __shared__ float lds[LR * LCF];          // 21120 B -> 7 blocks/CU
    const int cb  = blockIdx.x * TC;
    const int rb  = blockIdx.y * TR;
    const int tid = threadIdx.x;

    // Interior: every staged address (rows rb-2..rb+17, cols cb-4..cb+259) in-bounds.
    const bool interior = (blockIdx.x > 0) && (blockIdx.x < gridDim.x - 1) &&
                          (blockIdx.y > 0) && (blockIdx.y < gridDim.y - 1);

    // ---- Phase 1: stage 20x264 floats ----
    if (interior) {
#if HAS_GLL
        // Async direct-to-LDS: layout is linear (chunk lin -> lds byte lin*16),
        // wave-uniform base + lane*16 -- exactly global_load_lds's dest form.
        #pragma unroll
        for (int it = 0; it < (TOTCH + TPB - 1) / TPB; ++it) {
            const int lin = tid + it * TPB;
            if (it < TOTCH / TPB || lin < TOTCH) {
                const int lr = lin / NCHUNK;
                const int lc = lin - lr * NCHUNK;
                const float* gp = in + (size_t)(rb - 2 + lr) * W + (cb - 4) + lc * 4;
                gload_lds16(gp, &lds[lin * 4]);
            }
        }
#else
        #pragma unroll
        for (int it = 0; it < (TOTCH + TPB - 1) / TPB; ++it) {
            const int lin = tid + it * TPB;
            if (it < TOTCH / TPB || lin < TOTCH) {
                const int lr = lin / NCHUNK;
                const int lc = lin - lr * NCHUNK;
                f4 v = *(const f4*)(in + (size_t)(rb - 2 + lr) * W + (cb - 4) + lc * 4);
                *(f4*)(&lds[lin * 4]) = v;
            }
        }
#endif
    } else {
        // Border blocks (~7%): predicated VGPR path with zero-fill.
        #pragma unroll
        for (int it = 0; it < (TOTCH + TPB - 1) / TPB; ++it) {
            const int lin = tid + it * TPB;
            if (it < TOTCH / TPB || lin < TOTCH) {
                const int lr = lin / NCHUNK;
                const int lc = lin - lr * NCHUNK;
                const int gr = rb - 2 + lr;
                const int gc = cb - 4 + lc * 4;
                f4 v = {0.f, 0.f, 0.f, 0.f};
                if ((unsigned)gr < (unsigned)H && (unsigned)gc < (unsigned)W)
                    v = *(const f4*)(in + (size_t)gr * W + gc);
                *(f4*)(&lds[lin * 4]) = v;
            }
        }
    }
    __syncthreads();  // compiler emits s_waitcnt vmcnt(0) lgkmcnt(0) before barrier

    // ---- Phase 2: horizontal 5-sums from LDS + vertical register ring ----
    const int lx = tid & 63;                 // 64 column groups (4 floats each)
    const int ly = tid >> 6;                 // 4 row sub-bands (4 rows each)
    const int colf = lx * 4;
    const int o0 = ly * 4;

    float h[5][4];                           // ring of horizontal 5-sums
    auto hrow = [&](int lraw, float* hh) {
        const float* p = &lds[lraw * LCF + colf];
        f4 A = *(const f4*)(p);              // 16B lane stride -> conflict-free
        f4 B = *(const f4*)(p + 4);
        f4 C = *(const f4*)(p + 8);
        hh[0] = ((A[2] + A[3]) + (B[0] + B[1])) + B[2];
        hh[1] = ((A[3] + B[0]) + (B[1] + B[2])) + B[3];
        hh[2] = ((B[0] + B[1]) + (B[2] + B[3])) + C[0];
        hh[3] = ((B[1] + B[2]) + (B[3] + C[0])) + C[1];
    };

    #pragma unroll
    for (int k = 0; k < 4; ++k) hrow(o0 + k, h[k]);

    const float inv25 = 1.0f / 25.0f;
    float* outp = out + (size_t)(rb + o0) * W + cb + colf;

    #pragma unroll
    for (int i = 0; i < 4; ++i) {
        hrow(o0 + i + 4, h[(i + 4) % 5]);    // compile-time ring index
        f4 ov;
        #pragma unroll
        for (int j = 0; j < 4; ++j)
            ov[j] = (((h[0][j] + h[1][j]) + (h[2][j] + h[3][j])) + h[4][j]) * inv25;
        *(f4*)(outp) = ov;                   // aligned, coalesced
        outp += W;
    }
}

extern "C" void kernel_launch(void* const* d_in, const int* in_sizes, int n_in,
                              void* d_out, int out_size, void* d_ws, size_t ws_size,
                              hipStream_t stream) {
    const float* in = (const float*)d_in[0];
    // d_in[1] is the uniform 5x5 kernel = ones/25; folded into inv25.
    float* out = (float*)d_out;
    dim3 grid(W / TC, H / TR);               // (32, 512) = 16384 blocks
    box5_kernel<<<grid, dim3(TPB), 0, stream>>>(in, out);
}